// Round 2
// baseline (681.695 us; speedup 1.0000x reference)
//
#include <hip/hip_runtime.h>
#include <hip/hip_bf16.h>

#define NR 8192
#define DIN 512
#define DD 256

typedef __attribute__((ext_vector_type(8))) short short8;
typedef __attribute__((ext_vector_type(4))) float f32x4;

static __device__ __forceinline__ unsigned short f2bf(float x) {
    __hip_bfloat16 b = __float2bfloat16(x);
    return __builtin_bit_cast(unsigned short, b);
}
static __device__ __forceinline__ float bf2f(unsigned short u) {
    unsigned v = ((unsigned)u) << 16;
    return __builtin_bit_cast(float, v);
}

// ---------------------------------------------------------------------------
// K2: h = x @ W^T  (fp32-accurate via hi/lo bf16 split, 3 MFMA terms)
// grid (128, 2), block 256.  Tile 64 rows x 128 cols, BK=64.
// ---------------------------------------------------------------------------
__global__ __launch_bounds__(256) void k_gemm_h(
        const float* __restrict__ x, const float* __restrict__ W,
        float* __restrict__ h) {
    __shared__ unsigned short Ah[64][72], Al[64][72];
    __shared__ unsigned short Bh[128][72], Bl[128][72];
    const int t = threadIdx.x;
    const int i0 = blockIdx.x * 64;
    const int n0 = blockIdx.y * 128;
    const int lane = t & 63, q = lane >> 4, lm = lane & 15;
    const int w = t >> 6, wm = w >> 1, wn = w & 1;
    const int ar = t >> 2, ac0 = (t & 3) << 4;
    const int bn = t >> 1, bh0 = (t & 1) << 5;
    f32x4 acc[2][4];
#pragma unroll
    for (int mt = 0; mt < 2; ++mt)
#pragma unroll
        for (int nt = 0; nt < 4; ++nt) acc[mt][nt] = (f32x4){0.f, 0.f, 0.f, 0.f};

    for (int kb = 0; kb < DIN; kb += 64) {
        __syncthreads();
        {
            const float4* xp = (const float4*)(x + (size_t)(i0 + ar) * DIN + kb + ac0);
#pragma unroll
            for (int u = 0; u < 4; ++u) {
                float4 v = xp[u];
                unsigned short h0 = f2bf(v.x), h1 = f2bf(v.y), h2 = f2bf(v.z), h3 = f2bf(v.w);
                unsigned short l0 = f2bf(v.x - bf2f(h0)), l1 = f2bf(v.y - bf2f(h1));
                unsigned short l2 = f2bf(v.z - bf2f(h2)), l3 = f2bf(v.w - bf2f(h3));
                *(uint2*)&Ah[ar][ac0 + u * 4] =
                    make_uint2((unsigned)h0 | ((unsigned)h1 << 16), (unsigned)h2 | ((unsigned)h3 << 16));
                *(uint2*)&Al[ar][ac0 + u * 4] =
                    make_uint2((unsigned)l0 | ((unsigned)l1 << 16), (unsigned)l2 | ((unsigned)l3 << 16));
            }
            const float4* wp = (const float4*)(W + (size_t)(n0 + bn) * DIN + kb + bh0);
#pragma unroll
            for (int u = 0; u < 8; ++u) {
                float4 v = wp[u];
                unsigned short h0 = f2bf(v.x), h1 = f2bf(v.y), h2 = f2bf(v.z), h3 = f2bf(v.w);
                unsigned short l0 = f2bf(v.x - bf2f(h0)), l1 = f2bf(v.y - bf2f(h1));
                unsigned short l2 = f2bf(v.z - bf2f(h2)), l3 = f2bf(v.w - bf2f(h3));
                *(uint2*)&Bh[bn][bh0 + u * 4] =
                    make_uint2((unsigned)h0 | ((unsigned)h1 << 16), (unsigned)h2 | ((unsigned)h3 << 16));
                *(uint2*)&Bl[bn][bh0 + u * 4] =
                    make_uint2((unsigned)l0 | ((unsigned)l1 << 16), (unsigned)l2 | ((unsigned)l3 << 16));
            }
        }
        __syncthreads();
#pragma unroll
        for (int ks = 0; ks < 64; ks += 32) {
            short8 fa_h[2], fa_l[2], fb_h[4], fb_l[4];
#pragma unroll
            for (int mt = 0; mt < 2; ++mt) {
                int r = wm * 32 + mt * 16 + lm;
                fa_h[mt] = *(const short8*)&Ah[r][ks + q * 8];
                fa_l[mt] = *(const short8*)&Al[r][ks + q * 8];
            }
#pragma unroll
            for (int nt = 0; nt < 4; ++nt) {
                int c = wn * 64 + nt * 16 + lm;
                fb_h[nt] = *(const short8*)&Bh[c][ks + q * 8];
                fb_l[nt] = *(const short8*)&Bl[c][ks + q * 8];
            }
#pragma unroll
            for (int mt = 0; mt < 2; ++mt)
#pragma unroll
                for (int nt = 0; nt < 4; ++nt) {
                    acc[mt][nt] = __builtin_amdgcn_mfma_f32_16x16x32_bf16(fa_h[mt], fb_h[nt], acc[mt][nt], 0, 0, 0);
                    acc[mt][nt] = __builtin_amdgcn_mfma_f32_16x16x32_bf16(fa_h[mt], fb_l[nt], acc[mt][nt], 0, 0, 0);
                    acc[mt][nt] = __builtin_amdgcn_mfma_f32_16x16x32_bf16(fa_l[mt], fb_h[nt], acc[mt][nt], 0, 0, 0);
                }
        }
    }
#pragma unroll
    for (int mt = 0; mt < 2; ++mt)
#pragma unroll
        for (int nt = 0; nt < 4; ++nt)
#pragma unroll
            for (int rr = 0; rr < 4; ++rr) {
                int row = i0 + wm * 32 + mt * 16 + q * 4 + rr;
                int col = n0 + wn * 64 + nt * 16 + lm;
                h[(size_t)row * DD + col] = acc[mt][nt][rr];
            }
}

// ---------------------------------------------------------------------------
// K3a: s_j = h[j,:] . a[256:512]; one wave per row; block partial max.
// grid 2048, block 256.
// ---------------------------------------------------------------------------
__global__ __launch_bounds__(256) void k_s(
        const float* __restrict__ h, const float* __restrict__ a,
        float* __restrict__ s, float* __restrict__ pmax) {
    __shared__ float wmax[4];
    const int t = threadIdx.x, w = t >> 6, lane = t & 63;
    const int row = blockIdx.x * 4 + w;
    float4 hv = *(const float4*)(h + (size_t)row * DD + lane * 4);
    float4 av = *(const float4*)(a + DD + lane * 4);
    float d = hv.x * av.x + hv.y * av.y + hv.z * av.z + hv.w * av.w;
#pragma unroll
    for (int off = 32; off; off >>= 1) d += __shfl_down(d, off);
    if (lane == 0) { s[row] = d; wmax[w] = d; }
    __syncthreads();
    if (t == 0)
        pmax[blockIdx.x] = fmaxf(fmaxf(wmax[0], wmax[1]), fmaxf(wmax[2], wmax[3]));
}

// ---------------------------------------------------------------------------
// K3b: global max of pmax[2048], then e_j = exp(s_j - M).  grid 1, block 1024.
// ---------------------------------------------------------------------------
__global__ __launch_bounds__(1024) void k_e(
        const float* __restrict__ s, const float* __restrict__ pmax,
        float* __restrict__ e) {
    __shared__ float red[1024];
    const int t = threadIdx.x;
    red[t] = fmaxf(pmax[t], pmax[t + 1024]);
    __syncthreads();
    for (int off = 512; off; off >>= 1) {
        if (t < off) red[t] = fmaxf(red[t], red[t + off]);
        __syncthreads();
    }
    float M = red[0];
    for (int j = t; j < NR; j += 1024) e[j] = expf(s[j] - M);
}

// ---------------------------------------------------------------------------
// K4: g_t[d][j] = bf16(e_j * h[j][d])  (transposed, bf16) via LDS tile.
// grid (128, 4), block 256.
// ---------------------------------------------------------------------------
__global__ __launch_bounds__(256) void k_gt(
        const float* __restrict__ h, const float* __restrict__ e,
        unsigned short* __restrict__ gt) {
    __shared__ float tile[64][68];
    const int t = threadIdx.x;
    const int j0 = blockIdx.x * 64, d0 = blockIdx.y * 64;
    const int r = t >> 4, c4 = (t & 15) * 4;
#pragma unroll
    for (int rr = 0; rr < 4; ++rr) {
        int row = r + rr * 16;
        *(float4*)&tile[row][c4] = *(const float4*)(h + (size_t)(j0 + row) * DD + d0 + c4);
    }
    __syncthreads();
    float4 ev = *(const float4*)(e + j0 + c4);
#pragma unroll
    for (int rr = 0; rr < 4; ++rr) {
        int dd = r + rr * 16;
        unsigned short o0 = f2bf(ev.x * tile[c4 + 0][dd]);
        unsigned short o1 = f2bf(ev.y * tile[c4 + 1][dd]);
        unsigned short o2 = f2bf(ev.z * tile[c4 + 2][dd]);
        unsigned short o3 = f2bf(ev.w * tile[c4 + 3][dd]);
        *(uint2*)(gt + (size_t)(d0 + dd) * NR + j0 + c4) =
            make_uint2((unsigned)o0 | ((unsigned)o1 << 16), (unsigned)o2 | ((unsigned)o3 << 16));
    }
}

// ---------------------------------------------------------------------------
// K5 (fused): per block: 32 rows, full K=8192.
//   - stage adj tile -> As {0,1} bf16, accumulate denom, pack bits -> LDS bm
//   - stage gt tile  -> Bs
//   - MFMA num-accumulate (no k-split, no atomics)
//   - epilogue: out0 = elu(num/denom); alpha replayed from bitmask + e
// adj read from HBM exactly ONCE.  grid 256, block 512 (8 waves).
// LDS ~74 KB -> 2 blocks/CU.
// ---------------------------------------------------------------------------
__global__ __launch_bounds__(512, 4) void k_fused(
        const int* __restrict__ adj, const unsigned short* __restrict__ gt,
        const float* __restrict__ e, float* __restrict__ out0,
        float* __restrict__ alpha) {
    __shared__ unsigned short As[32][72];     //  4,608 B
    __shared__ unsigned short Bs[256][72];    // 36,864 B
    __shared__ unsigned bm[32][256];          // 32,768 B  (32 rows x 8192 bits)
    __shared__ float dnm_s[32];
    const int t = threadIdx.x;
    const int row0 = blockIdx.x * 32;
    const int lane = t & 63, q = lane >> 4, lm = lane & 15;
    const int w = t >> 6;
    const int ar = t >> 4, c = t & 15;        // adj staging: row ar, cols c*4+[0,4)
    const int bn = t >> 1, bo = (t & 1) * 32; // gt staging: row bn, 32 bf16 at bo

    f32x4 acc[2][2];
#pragma unroll
    for (int mt = 0; mt < 2; ++mt)
#pragma unroll
        for (int nt = 0; nt < 2; ++nt) acc[mt][nt] = (f32x4){0.f, 0.f, 0.f, 0.f};
    float dsum = 0.f;

    const int* ap = adj + (size_t)(row0 + ar) * NR + c * 4;
    const unsigned short* gp = gt + (size_t)bn * NR + bo;
    const float* ep = e + c * 4;

#pragma unroll 2
    for (int it = 0; it < 128; ++it) {
        __syncthreads();
        {
            int4 av = *(const int4*)(ap + (size_t)it * 64);
            float4 ev = *(const float4*)(ep + it * 64);
            // {0,1} bf16 packed pair
            unsigned p0 = (av.x ? 0x3F80u : 0u) | (av.y ? 0x3F800000u : 0u);
            unsigned p1 = (av.z ? 0x3F80u : 0u) | (av.w ? 0x3F800000u : 0u);
            dsum += (av.x ? ev.x : 0.f) + (av.y ? ev.y : 0.f) +
                    (av.z ? ev.z : 0.f) + (av.w ? ev.w : 0.f);
            *(uint2*)&As[ar][c * 4] = make_uint2(p0, p1);
            // bitmask: nibble per thread, OR-combined over 8 lanes -> 32b word
            unsigned nib = (av.x ? 1u : 0u) | (av.y ? 2u : 0u) |
                           (av.z ? 4u : 0u) | (av.w ? 8u : 0u);
            unsigned v = nib << ((c & 7) * 4);
            v |= __shfl_xor(v, 1);
            v |= __shfl_xor(v, 2);
            v |= __shfl_xor(v, 4);
            if ((c & 7) == 0) bm[ar][it * 2 + (c >> 3)] = v;
            // gt tile: 64 B per thread, contiguous
            const int4* gsrc = (const int4*)(gp + (size_t)it * 64);
            int4* bd = (int4*)&Bs[bn][bo];
            bd[0] = gsrc[0]; bd[1] = gsrc[1]; bd[2] = gsrc[2]; bd[3] = gsrc[3];
        }
        __syncthreads();
#pragma unroll
        for (int ks = 0; ks < 64; ks += 32) {
            short8 fa0 = *(const short8*)&As[lm][ks + q * 8];
            short8 fa1 = *(const short8*)&As[16 + lm][ks + q * 8];
            short8 fb0 = *(const short8*)&Bs[w * 32 + lm][ks + q * 8];
            short8 fb1 = *(const short8*)&Bs[w * 32 + 16 + lm][ks + q * 8];
            acc[0][0] = __builtin_amdgcn_mfma_f32_16x16x32_bf16(fa0, fb0, acc[0][0], 0, 0, 0);
            acc[0][1] = __builtin_amdgcn_mfma_f32_16x16x32_bf16(fa0, fb1, acc[0][1], 0, 0, 0);
            acc[1][0] = __builtin_amdgcn_mfma_f32_16x16x32_bf16(fa1, fb0, acc[1][0], 0, 0, 0);
            acc[1][1] = __builtin_amdgcn_mfma_f32_16x16x32_bf16(fa1, fb1, acc[1][1], 0, 0, 0);
        }
    }

    // ---- denom: 16 lanes (same t>>4) share a row ----
    dsum += __shfl_xor(dsum, 1);
    dsum += __shfl_xor(dsum, 2);
    dsum += __shfl_xor(dsum, 4);
    dsum += __shfl_xor(dsum, 8);
    if (c == 0) dnm_s[ar] = dsum;
    __syncthreads();
    if (t < 32) dnm_s[t] = 1.0f / dnm_s[t];
    __syncthreads();

    // ---- out0 = elu(num * invd) ----
#pragma unroll
    for (int mt = 0; mt < 2; ++mt)
#pragma unroll
        for (int nt = 0; nt < 2; ++nt)
#pragma unroll
            for (int rr = 0; rr < 4; ++rr) {
                int r = mt * 16 + q * 4 + rr;
                int cc = w * 32 + nt * 16 + lm;
                float z = acc[mt][nt][rr] * dnm_s[r];
                out0[(size_t)(row0 + r) * DD + cc] = z > 0.f ? z : expm1f(z);
            }

    // ---- alpha from bitmask ----
    const float invr = dnm_s[ar];
    float* arow = alpha + (size_t)(row0 + ar) * NR + c * 4;
#pragma unroll 4
    for (int it = 0; it < 128; ++it) {
        unsigned wv = bm[ar][it * 2 + (c >> 3)];
        unsigned nib = (wv >> ((c & 7) * 4)) & 15u;
        float4 ev = *(const float4*)(ep + it * 64);
        float4 o;
        o.x = (nib & 1u) ? ev.x * invr : 0.f;
        o.y = (nib & 2u) ? ev.y * invr : 0.f;
        o.z = (nib & 4u) ? ev.z * invr : 0.f;
        o.w = (nib & 8u) ? ev.w * invr : 0.f;
        *(float4*)(arow + (size_t)it * 64) = o;
    }
}

// ---------------------------------------------------------------------------
extern "C" void kernel_launch(void* const* d_in, const int* in_sizes, int n_in,
                              void* d_out, int out_size, void* d_ws, size_t ws_size,
                              hipStream_t stream) {
    const float* x = (const float*)d_in[0];
    const int* adj = (const int*)d_in[1];
    const float* W = (const float*)d_in[2];
    const float* a = (const float*)d_in[3];
    float* out0 = (float*)d_out;
    float* alpha = (float*)d_out + (size_t)NR * DD;

    char* ws = (char*)d_ws;
    float* h            = (float*)(ws + 0);          //  8,388,608 B
    float* s            = (float*)(ws + 8388608);    //     32,768 B
    float* pmax         = (float*)(ws + 8421376);    //      8,192 B
    float* e            = (float*)(ws + 8429568);    //     32,768 B
    unsigned short* gt  = (unsigned short*)(ws + 8462336);  // 4,194,304 B (end ~12.7 MB)

    k_gemm_h<<<dim3(128, 2), 256, 0, stream>>>(x, W, h);
    k_s<<<2048, 256, 0, stream>>>(h, a, s, pmax);
    k_e<<<1, 1024, 0, stream>>>(s, pmax, e);
    k_gt<<<dim3(128, 4), 256, 0, stream>>>(h, e, gt);
    k_fused<<<256, 512, 0, stream>>>(adj, gt, e, out0, alpha);
}

// Round 3
// 594.585 us; speedup vs baseline: 1.1465x; 1.1465x over previous
//
#include <hip/hip_runtime.h>
#include <hip/hip_bf16.h>

#define NR 8192
#define DIN 512
#define DD 256

typedef __attribute__((ext_vector_type(8))) short short8;
typedef __attribute__((ext_vector_type(4))) float f32x4;

static __device__ __forceinline__ unsigned short f2bf(float x) {
    __hip_bfloat16 b = __float2bfloat16(x);
    return __builtin_bit_cast(unsigned short, b);
}
static __device__ __forceinline__ float bf2f(unsigned short u) {
    unsigned v = ((unsigned)u) << 16;
    return __builtin_bit_cast(float, v);
}

// ---------------------------------------------------------------------------
// K2: h = x @ W^T  (fp32-accurate via hi/lo bf16 split, 3 MFMA terms)
// grid (128, 2), block 256.  Tile 64 rows x 128 cols, BK=64.
// ---------------------------------------------------------------------------
__global__ __launch_bounds__(256) void k_gemm_h(
        const float* __restrict__ x, const float* __restrict__ W,
        float* __restrict__ h) {
    __shared__ unsigned short Ah[64][72], Al[64][72];
    __shared__ unsigned short Bh[128][72], Bl[128][72];
    const int t = threadIdx.x;
    const int i0 = blockIdx.x * 64;
    const int n0 = blockIdx.y * 128;
    const int lane = t & 63, q = lane >> 4, lm = lane & 15;
    const int w = t >> 6, wm = w >> 1, wn = w & 1;
    const int ar = t >> 2, ac0 = (t & 3) << 4;
    const int bn = t >> 1, bh0 = (t & 1) << 5;
    f32x4 acc[2][4];
#pragma unroll
    for (int mt = 0; mt < 2; ++mt)
#pragma unroll
        for (int nt = 0; nt < 4; ++nt) acc[mt][nt] = (f32x4){0.f, 0.f, 0.f, 0.f};

    for (int kb = 0; kb < DIN; kb += 64) {
        __syncthreads();
        {
            const float4* xp = (const float4*)(x + (size_t)(i0 + ar) * DIN + kb + ac0);
#pragma unroll
            for (int u = 0; u < 4; ++u) {
                float4 v = xp[u];
                unsigned short h0 = f2bf(v.x), h1 = f2bf(v.y), h2 = f2bf(v.z), h3 = f2bf(v.w);
                unsigned short l0 = f2bf(v.x - bf2f(h0)), l1 = f2bf(v.y - bf2f(h1));
                unsigned short l2 = f2bf(v.z - bf2f(h2)), l3 = f2bf(v.w - bf2f(h3));
                *(uint2*)&Ah[ar][ac0 + u * 4] =
                    make_uint2((unsigned)h0 | ((unsigned)h1 << 16), (unsigned)h2 | ((unsigned)h3 << 16));
                *(uint2*)&Al[ar][ac0 + u * 4] =
                    make_uint2((unsigned)l0 | ((unsigned)l1 << 16), (unsigned)l2 | ((unsigned)l3 << 16));
            }
            const float4* wp = (const float4*)(W + (size_t)(n0 + bn) * DIN + kb + bh0);
#pragma unroll
            for (int u = 0; u < 8; ++u) {
                float4 v = wp[u];
                unsigned short h0 = f2bf(v.x), h1 = f2bf(v.y), h2 = f2bf(v.z), h3 = f2bf(v.w);
                unsigned short l0 = f2bf(v.x - bf2f(h0)), l1 = f2bf(v.y - bf2f(h1));
                unsigned short l2 = f2bf(v.z - bf2f(h2)), l3 = f2bf(v.w - bf2f(h3));
                *(uint2*)&Bh[bn][bh0 + u * 4] =
                    make_uint2((unsigned)h0 | ((unsigned)h1 << 16), (unsigned)h2 | ((unsigned)h3 << 16));
                *(uint2*)&Bl[bn][bh0 + u * 4] =
                    make_uint2((unsigned)l0 | ((unsigned)l1 << 16), (unsigned)l2 | ((unsigned)l3 << 16));
            }
        }
        __syncthreads();
#pragma unroll
        for (int ks = 0; ks < 64; ks += 32) {
            short8 fa_h[2], fa_l[2], fb_h[4], fb_l[4];
#pragma unroll
            for (int mt = 0; mt < 2; ++mt) {
                int r = wm * 32 + mt * 16 + lm;
                fa_h[mt] = *(const short8*)&Ah[r][ks + q * 8];
                fa_l[mt] = *(const short8*)&Al[r][ks + q * 8];
            }
#pragma unroll
            for (int nt = 0; nt < 4; ++nt) {
                int c = wn * 64 + nt * 16 + lm;
                fb_h[nt] = *(const short8*)&Bh[c][ks + q * 8];
                fb_l[nt] = *(const short8*)&Bl[c][ks + q * 8];
            }
#pragma unroll
            for (int mt = 0; mt < 2; ++mt)
#pragma unroll
                for (int nt = 0; nt < 4; ++nt) {
                    acc[mt][nt] = __builtin_amdgcn_mfma_f32_16x16x32_bf16(fa_h[mt], fb_h[nt], acc[mt][nt], 0, 0, 0);
                    acc[mt][nt] = __builtin_amdgcn_mfma_f32_16x16x32_bf16(fa_h[mt], fb_l[nt], acc[mt][nt], 0, 0, 0);
                    acc[mt][nt] = __builtin_amdgcn_mfma_f32_16x16x32_bf16(fa_l[mt], fb_h[nt], acc[mt][nt], 0, 0, 0);
                }
        }
    }
#pragma unroll
    for (int mt = 0; mt < 2; ++mt)
#pragma unroll
        for (int nt = 0; nt < 4; ++nt)
#pragma unroll
            for (int rr = 0; rr < 4; ++rr) {
                int row = i0 + wm * 32 + mt * 16 + q * 4 + rr;
                int col = n0 + wn * 64 + nt * 16 + lm;
                h[(size_t)row * DD + col] = acc[mt][nt][rr];
            }
}

// ---------------------------------------------------------------------------
// K3a: s_j = h[j,:] . a[256:512]; one wave per row; block partial max.
// ---------------------------------------------------------------------------
__global__ __launch_bounds__(256) void k_s(
        const float* __restrict__ h, const float* __restrict__ a,
        float* __restrict__ s, float* __restrict__ pmax) {
    __shared__ float wmax[4];
    const int t = threadIdx.x, w = t >> 6, lane = t & 63;
    const int row = blockIdx.x * 4 + w;
    float4 hv = *(const float4*)(h + (size_t)row * DD + lane * 4);
    float4 av = *(const float4*)(a + DD + lane * 4);
    float d = hv.x * av.x + hv.y * av.y + hv.z * av.z + hv.w * av.w;
#pragma unroll
    for (int off = 32; off; off >>= 1) d += __shfl_down(d, off);
    if (lane == 0) { s[row] = d; wmax[w] = d; }
    __syncthreads();
    if (t == 0)
        pmax[blockIdx.x] = fmaxf(fmaxf(wmax[0], wmax[1]), fmaxf(wmax[2], wmax[3]));
}

// ---------------------------------------------------------------------------
// K3b: global max of pmax[2048], then e_j = exp(s_j - M).
// ---------------------------------------------------------------------------
__global__ __launch_bounds__(1024) void k_e(
        const float* __restrict__ s, const float* __restrict__ pmax,
        float* __restrict__ e) {
    __shared__ float red[1024];
    const int t = threadIdx.x;
    red[t] = fmaxf(pmax[t], pmax[t + 1024]);
    __syncthreads();
    for (int off = 512; off; off >>= 1) {
        if (t < off) red[t] = fmaxf(red[t], red[t + off]);
        __syncthreads();
    }
    float M = red[0];
    for (int j = t; j < NR; j += 1024) e[j] = expf(s[j] - M);
}

// ---------------------------------------------------------------------------
// K4: g_t[d][j] = bf16(e_j * h[j][d])  (transposed, bf16) via LDS tile.
// ---------------------------------------------------------------------------
__global__ __launch_bounds__(256) void k_gt(
        const float* __restrict__ h, const float* __restrict__ e,
        unsigned short* __restrict__ gt) {
    __shared__ float tile[64][68];
    const int t = threadIdx.x;
    const int j0 = blockIdx.x * 64, d0 = blockIdx.y * 64;
    const int r = t >> 4, c4 = (t & 15) * 4;
#pragma unroll
    for (int rr = 0; rr < 4; ++rr) {
        int row = r + rr * 16;
        *(float4*)&tile[row][c4] = *(const float4*)(h + (size_t)(j0 + row) * DD + d0 + c4);
    }
    __syncthreads();
    float4 ev = *(const float4*)(e + j0 + c4);
#pragma unroll
    for (int rr = 0; rr < 4; ++rr) {
        int dd = r + rr * 16;
        unsigned short o0 = f2bf(ev.x * tile[c4 + 0][dd]);
        unsigned short o1 = f2bf(ev.y * tile[c4 + 1][dd]);
        unsigned short o2 = f2bf(ev.z * tile[c4 + 2][dd]);
        unsigned short o3 = f2bf(ev.w * tile[c4 + 3][dd]);
        *(uint2*)(gt + (size_t)(d0 + dd) * NR + j0 + c4) =
            make_uint2((unsigned)o0 | ((unsigned)o1 << 16), (unsigned)o2 | ((unsigned)o3 << 16));
    }
}

// ---------------------------------------------------------------------------
// K5 (fused, restructured): 32 rows/block, full K=8192, grid 256 = 1 block/CU,
// block 1024 (16 waves).
//   - adj tile prefetched into REGISTERS one iteration ahead
//   - A stored in LDS in MFMA *fragment* layout (lane-linear ds_read_b128,
//     conflict-free); only ~8.3 KB LDS total
//   - B fragments loaded DIRECTLY from global gt (L2-resident, already in
//     fragment order: 16 B/lane contiguous)
//   - adj bitmask kept in VGPRs (8 uints/thread); alpha replayed from it
// adj read from HBM exactly once; no atomics; no memsets.
// ---------------------------------------------------------------------------
__global__ __launch_bounds__(1024, 4) void k_fused(
        const int* __restrict__ adj, const unsigned short* __restrict__ gt,
        const float* __restrict__ e, float* __restrict__ out0,
        float* __restrict__ alpha) {
    // A fragments: [mt][s][lane*8+j] shorts = 2*4*512 shorts = 8 KB
    __shared__ unsigned short As_f[2 * 4 * 512];
    __shared__ float dnm_s[32];
    const int t = threadIdx.x;
    const int row0 = blockIdx.x * 32;
    const int lane = t & 63, q = lane >> 4, lm = lane & 15;
    const int w = t >> 6;                     // 16 waves, each owns 16 cols
    const int ar = t >> 5, c = t & 31;        // staging: row ar, cols c*4..+3

    // fragment-layout write offset (constant per thread), in shorts:
    //   k_local = 4c+u -> s=c>>3, q'=(c>>1)&3, j=(c&1)*4+u, m=ar&15, mt=ar>>4
    const int woff = (ar >> 4) * 2048 + (c >> 3) * 512 +
                     (((c >> 1) & 3) * 16 + (ar & 15)) * 8 + (c & 1) * 4;

    f32x4 acc[2];
    acc[0] = (f32x4){0.f, 0.f, 0.f, 0.f};
    acc[1] = (f32x4){0.f, 0.f, 0.f, 0.f};
    unsigned bits[8] = {0, 0, 0, 0, 0, 0, 0, 0};
    float dsum = 0.f;

    const int* ap = adj + (size_t)(row0 + ar) * NR + c * 4;
    const float* ep = e + c * 4;
    // B fragment base: row n = w*16+lm of gt, k-offset q*8
    const unsigned short* gb = gt + (size_t)(w * 16 + lm) * NR + q * 8;

    int4 pa = *(const int4*)ap;  // prefetch tile 0

#pragma unroll 2
    for (int it = 0; it < 64; ++it) {
        // ---- convert prefetched adj (registers) ----
        float4 ev = *(const float4*)(ep + it * 128);
        unsigned p0 = (pa.x ? 0x3F80u : 0u) | (pa.y ? 0x3F800000u : 0u);
        unsigned p1 = (pa.z ? 0x3F80u : 0u) | (pa.w ? 0x3F800000u : 0u);
        dsum += (pa.x ? ev.x : 0.f) + (pa.y ? ev.y : 0.f) +
                (pa.z ? ev.z : 0.f) + (pa.w ? ev.w : 0.f);
        unsigned nib = (pa.x ? 1u : 0u) | (pa.y ? 2u : 0u) |
                       (pa.z ? 4u : 0u) | (pa.w ? 8u : 0u);
        bits[it >> 3] |= nib << ((it & 7) * 4);
        __syncthreads();                       // (a) prev compute done with As_f
        *(uint2*)&As_f[woff] = make_uint2(p0, p1);
        // issue next prefetch NOW — latency overlaps barrier(b) + compute
        pa = *(const int4*)(ap + (size_t)(((it + 1) & 63) * 128));
        __syncthreads();                       // (b) As_f ready
        // ---- compute: A frags from LDS (lane-linear), B frags from global ----
#pragma unroll
        for (int s = 0; s < 4; ++s) {
            short8 fa0 = *(const short8*)&As_f[s * 512 + lane * 8];
            short8 fa1 = *(const short8*)&As_f[2048 + s * 512 + lane * 8];
            short8 fb = *(const short8*)(gb + (size_t)it * 128 + s * 32);
            acc[0] = __builtin_amdgcn_mfma_f32_16x16x32_bf16(fa0, fb, acc[0], 0, 0, 0);
            acc[1] = __builtin_amdgcn_mfma_f32_16x16x32_bf16(fa1, fb, acc[1], 0, 0, 0);
        }
    }

    // ---- denom: 32 lanes (same ar) share a row; they sit in one half-wave ----
    dsum += __shfl_xor(dsum, 1);
    dsum += __shfl_xor(dsum, 2);
    dsum += __shfl_xor(dsum, 4);
    dsum += __shfl_xor(dsum, 8);
    dsum += __shfl_xor(dsum, 16);
    if (c == 0) dnm_s[ar] = dsum;
    __syncthreads();
    if (t < 32) dnm_s[t] = 1.0f / dnm_s[t];
    __syncthreads();

    // ---- out0 = elu(num * invd) ----
#pragma unroll
    for (int mt = 0; mt < 2; ++mt)
#pragma unroll
        for (int rr = 0; rr < 4; ++rr) {
            int r = mt * 16 + q * 4 + rr;
            int cc = w * 16 + lm;
            float z = acc[mt][rr] * dnm_s[r];
            out0[(size_t)(row0 + r) * DD + cc] = z > 0.f ? z : expm1f(z);
        }

    // ---- alpha replay from VGPR bitmask ----
    const float invr = dnm_s[ar];
    float* arow = alpha + (size_t)(row0 + ar) * NR + c * 4;
#pragma unroll 4
    for (int it = 0; it < 64; ++it) {
        unsigned nib = (bits[it >> 3] >> ((it & 7) * 4)) & 15u;
        float4 ev = *(const float4*)(ep + it * 128);
        float4 o;
        o.x = (nib & 1u) ? ev.x * invr : 0.f;
        o.y = (nib & 2u) ? ev.y * invr : 0.f;
        o.z = (nib & 4u) ? ev.z * invr : 0.f;
        o.w = (nib & 8u) ? ev.w * invr : 0.f;
        *(float4*)(arow + (size_t)it * 128) = o;
    }
}

// ---------------------------------------------------------------------------
extern "C" void kernel_launch(void* const* d_in, const int* in_sizes, int n_in,
                              void* d_out, int out_size, void* d_ws, size_t ws_size,
                              hipStream_t stream) {
    const float* x = (const float*)d_in[0];
    const int* adj = (const int*)d_in[1];
    const float* W = (const float*)d_in[2];
    const float* a = (const float*)d_in[3];
    float* out0 = (float*)d_out;
    float* alpha = (float*)d_out + (size_t)NR * DD;

    char* ws = (char*)d_ws;
    float* h            = (float*)(ws + 0);          //  8,388,608 B
    float* s            = (float*)(ws + 8388608);    //     32,768 B
    float* pmax         = (float*)(ws + 8421376);    //      8,192 B
    float* e            = (float*)(ws + 8429568);    //     32,768 B
    unsigned short* gt  = (unsigned short*)(ws + 8462336);  // 4,194,304 B (end ~12.7 MB)

    k_gemm_h<<<dim3(128, 2), 256, 0, stream>>>(x, W, h);
    k_s<<<2048, 256, 0, stream>>>(h, a, s, pmax);
    k_e<<<1, 1024, 0, stream>>>(s, pmax, e);
    k_gt<<<dim3(128, 4), 256, 0, stream>>>(h, e, gt);
    k_fused<<<256, 1024, 0, stream>>>(adj, gt, e, out0, alpha);
}